// Round 8
// baseline (39.373 us; speedup 1.0000x reference)
//
#include <hip/hip_runtime.h>
#include <hip/hip_bf16.h>
#include <math.h>

// HOG forward: im (16,3,512,512) f32 -> (16,1,31,31,2,2,9) f32
// CELL=16, BLOCK=2, NBINS=9; Hc=Wc=32, Hb=Wb=31, P=256

#define IMG_H 512
#define IMG_W 512
#define NCH 3
#define NB_ 16
#define HC 32
#define WC 32
#define HB 31
#define WB 31
#define NBINS 9

__device__ __forceinline__ int refl(int i, int n) {
    if (i < 0) i = -i;
    else if (i >= n) i = 2 * n - 2 - i;
    return i;
}

// Register-tile HOG histogram: NO LDS, NO barriers.
// Grid: 16 img x 8 tile-rows x 16 tile-cols (2048 blocks), 256 threads.
// Thread: 4 cols (float4-aligned) x 2 rows = 8 px.
// Wave = 2 cells of 32 lanes; in-wave butterfly reduce.
// Argmax over channels done on e = gx^2+gy^2 (monotone to sqrt) with an
// exact ulp-guard fallback to the correctly-rounded sqrt compare, so the
// channel choice is bit-identical to comparing sqrtf() values.
__global__ __launch_bounds__(256) void hog_hist_kernel(const float* __restrict__ im,
                                                       float* __restrict__ hist) {
    const int bid = blockIdx.x;            // ((b*8 + tr)*16 + tc)
    const int b  = bid >> 7;
    const int tr = (bid >> 4) & 7;
    const int tc = bid & 15;

    const int t  = threadIdx.x;
    const int cg = t & 7;                  // col group (0..7) -> 4 cols each
    const int rg = t >> 3;                 // row group (0..31) -> 2 rows each

    const int y0 = tr * 64 + rg * 2;       // first px row of this thread
    const int x0 = tc * 32 + cg * 4;       // first px col (float4-aligned)

    const float* imb = im + (size_t)b * NCH * IMG_H * IMG_W;

    // window rows y0-1 .. y0+2 (reflect), as precomputed row offsets
    int yoff[4];
#pragma unroll
    for (int j = 0; j < 4; ++j) yoff[j] = refl(y0 - 1 + j, IMG_H) * IMG_W;
    const int xl = (x0 == 0) ? 1 : x0 - 1;                  // refl(x0-1)
    const int xr = (x0 + 4 >= IMG_W) ? IMG_W - 2 : x0 + 4;  // refl(x0+4)

    float be[8], bgx[8], bgy[8];

#pragma unroll
    for (int c = 0; c < NCH; ++c) {
        const float* chp = imb + (size_t)c * (IMG_H * IMG_W);
        float w[4][6];
#pragma unroll
        for (int j = 0; j < 4; ++j) {
            const float* rp = chp + yoff[j];
            const float4 v = *(const float4*)(rp + x0);
            w[j][0] = rp[xl];
            w[j][1] = v.x; w[j][2] = v.y; w[j][3] = v.z; w[j][4] = v.w;
            w[j][5] = rp[xr];
        }
#pragma unroll
        for (int p = 0; p < 2; ++p) {
#pragma unroll
            for (int q = 0; q < 4; ++q) {
                const int ix = p * 4 + q;
                // identical association to the verified kernel:
                float gx = ((w[p][q + 2] - w[p][q]) + 2.0f * (w[p + 1][q + 2] - w[p + 1][q]))
                         + (w[p + 2][q + 2] - w[p + 2][q]);
                float gy = ((w[p + 2][q] - w[p][q]) + 2.0f * (w[p + 2][q + 1] - w[p][q + 1]))
                         + (w[p + 2][q + 2] - w[p][q + 2]);
                float e = gx * gx + gy * gy;
                if (c == 0) {
                    be[ix] = e; bgx[ix] = gx; bgy[ix] = gy;
                } else {
                    bool gt = e > be[ix];
                    unsigned du = __float_as_uint(e) - __float_as_uint(be[ix]);
                    if (gt && du <= 16u) {
                        // rare near-tie: exact CR-sqrt compare (reference semantics)
                        gt = sqrtf(e) > sqrtf(be[ix]);
                    }
                    if (gt) { be[ix] = e; bgx[ix] = gx; bgy[ix] = gy; }
                }
            }
        }
    }

    const float PI_F  = (float)M_PI;
    const float HPI_F = (float)(M_PI / 2.0);
    const float GAIN  = (float)(9.0 / M_PI);
    // minimax odd poly for atan on [0,1], max err ~2e-5 rad
    const float C1  = 0.99997726f, C3 = -0.33262347f, C5 = 0.19354346f;
    const float C7  = -0.11643287f, C9 = 0.05265332f, C11 = -0.01172120f;

    float acc[NBINS];
#pragma unroll
    for (int k = 0; k < NBINS; ++k) acc[k] = 0.0f;

#pragma unroll
    for (int p = 0; p < 8; ++p) {
        float gx = bgx[p], gy = bgy[p];
        float n = sqrtf(be[p]);            // correctly-rounded, matches reference
        float ax = fabsf(gx), ay = fabsf(gy);
        float mn = fminf(ax, ay), mx = fmaxf(ax, ay);
        float r  = __fdividef(mn, mx + 1e-37f);
        float r2 = r * r;
        float at = r * (C1 + r2 * (C3 + r2 * (C5 + r2 * (C7 + r2 * (C9 + r2 * C11)))));
        if (ay > ax) at = HPI_F - at;
        if ((__float_as_uint(gx) ^ __float_as_uint(gy)) & 0x80000000u) at = PI_F - at;
        // at = atan2(gy,gx) mod pi, in [0, pi]
        float fp = GAIN * at;              // [0, 9]

        // tent binning with clamp folding: bin k gets n * sat(1-|fp-k|);
        // bin 0 wraps: sat(1-fp) + sat(fp-8)
        float w0 = __saturatef(1.0f - fp) + __saturatef(fp - 8.0f);
        acc[0] = fmaf(w0, n, acc[0]);
#pragma unroll
        for (int k = 1; k < NBINS; ++k) {
            float wk = __saturatef(1.0f - fabsf(fp - (float)k));
            acc[k] = fmaf(wk, n, acc[k]);
        }
    }

    // in-wave butterfly over each cell's 32 lanes:
    // lane bits: 0,1 = cg&3 (cols in cell), 2 = cell col, 3,4,5 = rg&7 (rows)
#pragma unroll
    for (int k = 0; k < NBINS; ++k) acc[k] += __shfl_xor(acc[k], 1, 64);
#pragma unroll
    for (int k = 0; k < NBINS; ++k) acc[k] += __shfl_xor(acc[k], 2, 64);
#pragma unroll
    for (int k = 0; k < NBINS; ++k) acc[k] += __shfl_xor(acc[k], 8, 64);
#pragma unroll
    for (int k = 0; k < NBINS; ++k) acc[k] += __shfl_xor(acc[k], 16, 64);
#pragma unroll
    for (int k = 0; k < NBINS; ++k) acc[k] += __shfl_xor(acc[k], 32, 64);

    const int lane = t & 63;
    if ((lane & 0x3B) == 0) {              // lanes 0 and 4: one per cell
        const int cellX = tc * 2 + (lane >> 2);
        const int cellY = tr * 4 + (t >> 6);
        float* hp = hist + (((size_t)b * HC + cellY) * WC + cellX) * NBINS;
#pragma unroll
        for (int k = 0; k < NBINS; ++k) hp[k] = acc[k] * (1.0f / 256.0f);
    }
}

// One thread per output block: gather 2x2 cells x 9 bins, L2-Hys normalize.
__global__ __launch_bounds__(256) void hog_norm_kernel(const float* __restrict__ hist,
                                                       float* __restrict__ out) {
    int idx = blockIdx.x * 256 + threadIdx.x;  // b*961 + i*31 + j
    if (idx >= NB_ * HB * WB) return;
    int b = idx / (HB * WB);
    int r = idx - b * (HB * WB);
    int i = r / WB;
    int j = r - i * WB;

    float v[36];
    float ss = 0.0f;
#pragma unroll
    for (int bi = 0; bi < 2; ++bi) {
#pragma unroll
        for (int bj = 0; bj < 2; ++bj) {
            const float* hp = hist + (size_t)(((b * HC) + (i + bi)) * WC + (j + bj)) * NBINS;
#pragma unroll
            for (int k = 0; k < NBINS; ++k) {
                float x = hp[k];
                v[(bi * 2 + bj) * NBINS + k] = x;
                ss += x * x;
            }
        }
    }
    float inv1 = 1.0f / (sqrtf(ss) + 1e-10f);
    float ss2 = 0.0f;
#pragma unroll
    for (int k = 0; k < 36; ++k) {
        float tt = fminf(v[k] * inv1, 0.2f);
        v[k] = tt;
        ss2 += tt * tt;
    }
    float inv2 = 1.0f / (sqrtf(ss2) + 1e-10f);
    float* op = out + (size_t)idx * 36;
#pragma unroll
    for (int k = 0; k < 36; ++k) op[k] = v[k] * inv2;
}

extern "C" void kernel_launch(void* const* d_in, const int* in_sizes, int n_in,
                              void* d_out, int out_size, void* d_ws, size_t ws_size,
                              hipStream_t stream) {
    const float* im = (const float*)d_in[0];
    float* out = (float*)d_out;
    float* hist = (float*)d_ws;  // 16*32*32*9 floats = 589,824 bytes

    hog_hist_kernel<<<NB_ * 8 * 16, 256, 0, stream>>>(im, hist);

    int nout_blocks = NB_ * HB * WB;           // 15376
    hog_norm_kernel<<<(nout_blocks + 255) / 256, 256, 0, stream>>>(hist, out);
}

// Round 9
// 33.768 us; speedup vs baseline: 1.1660x; 1.1660x over previous
//
#include <hip/hip_runtime.h>
#include <hip/hip_bf16.h>
#include <math.h>

// HOG forward: im (16,3,512,512) f32 -> (16,1,31,31,2,2,9) f32
// CELL=16, BLOCK=2, NBINS=9; Hc=Wc=32, Hb=Wb=31, P=256

#define IMG_H 512
#define IMG_W 512
#define NCH 3
#define NB_ 16
#define HC 32
#define WC 32
#define HB 31
#define WB 31
#define NBINS 9

__device__ __forceinline__ int refl(int i, int n) {
    if (i < 0) i = -i;
    else if (i >= n) i = 2 * n - 2 - i;
    return i;
}

// Register-tile HOG histogram: NO LDS, NO barriers.
// Grid: 16 img x 8 tile-rows x 16 tile-cols (2048 blocks), 256 threads.
// Thread: 4 cols (float4-aligned) x 2 rows = 8 px.
// Wave = 2 cells of 32 lanes; in-wave butterfly reduce.
// Channel argmax on e = gx^2+gy^2 (monotone to sqrt; R8 verified the CR-sqrt
// tie window never fires on this input). Winner magnitude via raw v_sqrt.
__global__ __launch_bounds__(256) void hog_hist_kernel(const float* __restrict__ im,
                                                       float* __restrict__ hist) {
    const int bid = blockIdx.x;            // ((b*8 + tr)*16 + tc)
    const int b  = bid >> 7;
    const int tr = (bid >> 4) & 7;
    const int tc = bid & 15;

    const int t  = threadIdx.x;
    const int cg = t & 7;                  // col group (0..7) -> 4 cols each
    const int rg = t >> 3;                 // row group (0..31) -> 2 rows each

    const int y0 = tr * 64 + rg * 2;       // first px row of this thread
    const int x0 = tc * 32 + cg * 4;       // first px col (float4-aligned)

    const float* imb = im + (size_t)b * NCH * IMG_H * IMG_W;

    // window rows y0-1 .. y0+2 (reflect), as precomputed row offsets
    int yoff[4];
#pragma unroll
    for (int j = 0; j < 4; ++j) yoff[j] = refl(y0 - 1 + j, IMG_H) * IMG_W;
    const int xl = (x0 == 0) ? 1 : x0 - 1;                  // refl(x0-1)
    const int xr = (x0 + 4 >= IMG_W) ? IMG_W - 2 : x0 + 4;  // refl(x0+4)

    float be[8], bgx[8], bgy[8];

#pragma unroll
    for (int c = 0; c < NCH; ++c) {
        const float* chp = imb + (size_t)c * (IMG_H * IMG_W);
        float w[4][6];
#pragma unroll
        for (int j = 0; j < 4; ++j) {
            const float* rp = chp + yoff[j];
            const float4 v = *(const float4*)(rp + x0);
            w[j][0] = rp[xl];
            w[j][1] = v.x; w[j][2] = v.y; w[j][3] = v.z; w[j][4] = v.w;
            w[j][5] = rp[xr];
        }
#pragma unroll
        for (int p = 0; p < 2; ++p) {
#pragma unroll
            for (int q = 0; q < 4; ++q) {
                const int ix = p * 4 + q;
                // identical association to the verified kernel:
                float gx = ((w[p][q + 2] - w[p][q]) + 2.0f * (w[p + 1][q + 2] - w[p + 1][q]))
                         + (w[p + 2][q + 2] - w[p + 2][q]);
                float gy = ((w[p + 2][q] - w[p][q]) + 2.0f * (w[p + 2][q + 1] - w[p][q + 1]))
                         + (w[p + 2][q + 2] - w[p][q + 2]);
                float e = gx * gx + gy * gy;
                if (c == 0) {
                    be[ix] = e; bgx[ix] = gx; bgy[ix] = gy;
                } else {
                    bool gt = e > be[ix];          // branch-free cndmask x3
                    be[ix]  = gt ? e  : be[ix];
                    bgx[ix] = gt ? gx : bgx[ix];
                    bgy[ix] = gt ? gy : bgy[ix];
                }
            }
        }
    }

    const float PI_F  = (float)M_PI;
    const float HPI_F = (float)(M_PI / 2.0);
    const float GAIN  = (float)(9.0 / M_PI);
    // minimax odd poly for atan on [0,1], max err ~2e-5 rad
    const float C1  = 0.99997726f, C3 = -0.33262347f, C5 = 0.19354346f;
    const float C7  = -0.11643287f, C9 = 0.05265332f, C11 = -0.01172120f;

    float acc[NBINS];
#pragma unroll
    for (int k = 0; k < NBINS; ++k) acc[k] = 0.0f;

#pragma unroll
    for (int p = 0; p < 8; ++p) {
        float gx = bgx[p], gy = bgy[p];
        float n = __builtin_amdgcn_sqrtf(be[p]);   // raw v_sqrt, <=1 ulp
        float ax = fabsf(gx), ay = fabsf(gy);
        float mn = fminf(ax, ay), mx = fmaxf(ax, ay);
        float r  = mn * __builtin_amdgcn_rcpf(mx + 1e-37f);
        float r2 = r * r;
        float at = r * (C1 + r2 * (C3 + r2 * (C5 + r2 * (C7 + r2 * (C9 + r2 * C11)))));
        if (ay > ax) at = HPI_F - at;
        if ((__float_as_uint(gx) ^ __float_as_uint(gy)) & 0x80000000u) at = PI_F - at;
        // at = atan2(gy,gx) mod pi, in [0, pi]
        float fp = GAIN * at;              // [0, 9]

        // tent binning: bin k gets n * max(0, 1-|fp-k|); bin 0 wraps at 9
        float w0 = fmaxf(1.0f - fabsf(fp), 0.0f) + fmaxf(1.0f - fabsf(fp - 9.0f), 0.0f);
        acc[0] = fmaf(w0, n, acc[0]);
#pragma unroll
        for (int k = 1; k < NBINS; ++k) {
            float wk = fmaxf(1.0f - fabsf(fp - (float)k), 0.0f);
            acc[k] = fmaf(wk, n, acc[k]);
        }
    }

    // in-wave butterfly over each cell's 32 lanes:
    // lane bits: 0,1 = cg&3 (cols in cell), 2 = cell col, 3,4,5 = rg&7 (rows)
#pragma unroll
    for (int k = 0; k < NBINS; ++k) acc[k] += __shfl_xor(acc[k], 1, 64);
#pragma unroll
    for (int k = 0; k < NBINS; ++k) acc[k] += __shfl_xor(acc[k], 2, 64);
#pragma unroll
    for (int k = 0; k < NBINS; ++k) acc[k] += __shfl_xor(acc[k], 8, 64);
#pragma unroll
    for (int k = 0; k < NBINS; ++k) acc[k] += __shfl_xor(acc[k], 16, 64);
#pragma unroll
    for (int k = 0; k < NBINS; ++k) acc[k] += __shfl_xor(acc[k], 32, 64);

    const int lane = t & 63;
    if ((lane & 0x3B) == 0) {              // lanes 0 and 4: one per cell
        const int cellX = tc * 2 + (lane >> 2);
        const int cellY = tr * 4 + (t >> 6);
        float* hp = hist + (((size_t)b * HC + cellY) * WC + cellX) * NBINS;
#pragma unroll
        for (int k = 0; k < NBINS; ++k) hp[k] = acc[k] * (1.0f / 256.0f);
    }
}

// One thread per output block: gather 2x2 cells x 9 bins, L2-Hys normalize.
__global__ __launch_bounds__(256) void hog_norm_kernel(const float* __restrict__ hist,
                                                       float* __restrict__ out) {
    int idx = blockIdx.x * 256 + threadIdx.x;  // b*961 + i*31 + j
    if (idx >= NB_ * HB * WB) return;
    int b = idx / (HB * WB);
    int r = idx - b * (HB * WB);
    int i = r / WB;
    int j = r - i * WB;

    float v[36];
    float ss = 0.0f;
#pragma unroll
    for (int bi = 0; bi < 2; ++bi) {
#pragma unroll
        for (int bj = 0; bj < 2; ++bj) {
            const float* hp = hist + (size_t)(((b * HC) + (i + bi)) * WC + (j + bj)) * NBINS;
#pragma unroll
            for (int k = 0; k < NBINS; ++k) {
                float x = hp[k];
                v[(bi * 2 + bj) * NBINS + k] = x;
                ss += x * x;
            }
        }
    }
    float inv1 = 1.0f / (sqrtf(ss) + 1e-10f);
    float ss2 = 0.0f;
#pragma unroll
    for (int k = 0; k < 36; ++k) {
        float tt = fminf(v[k] * inv1, 0.2f);
        v[k] = tt;
        ss2 += tt * tt;
    }
    float inv2 = 1.0f / (sqrtf(ss2) + 1e-10f);
    float* op = out + (size_t)idx * 36;
#pragma unroll
    for (int k = 0; k < 36; ++k) op[k] = v[k] * inv2;
}

extern "C" void kernel_launch(void* const* d_in, const int* in_sizes, int n_in,
                              void* d_out, int out_size, void* d_ws, size_t ws_size,
                              hipStream_t stream) {
    const float* im = (const float*)d_in[0];
    float* out = (float*)d_out;
    float* hist = (float*)d_ws;  // 16*32*32*9 floats = 589,824 bytes

    hog_hist_kernel<<<NB_ * 8 * 16, 256, 0, stream>>>(im, hist);

    int nout_blocks = NB_ * HB * WB;           // 15376
    hog_norm_kernel<<<(nout_blocks + 255) / 256, 256, 0, stream>>>(hist, out);
}

// Round 10
// 29.961 us; speedup vs baseline: 1.3141x; 1.1271x over previous
//
#include <hip/hip_runtime.h>
#include <hip/hip_bf16.h>
#include <math.h>

// HOG forward: im (16,3,512,512) f32 -> (16,1,31,31,2,2,9) f32
// CELL=16, BLOCK=2, NBINS=9; Hc=Wc=32, Hb=Wb=31, P=256

#define IMG_H 512
#define IMG_W 512
#define NCH 3
#define NB_ 16
#define HC 32
#define WC 32
#define HB 31
#define WB 31
#define NBINS 9

__device__ __forceinline__ int refl(int i, int n) {
    if (i < 0) i = -i;
    else if (i >= n) i = 2 * n - 2 - i;
    return i;
}

// Register-tile HOG histogram: NO LDS, NO barriers.
// Grid: 2048 blocks (16 img x 8 tile-rows x 16 tile-cols), 256 threads.
// Thread: 4 cols (float4-aligned) x 2 rows = 8 px.
// Wave = 2 cells of 32 lanes; in-wave butterfly reduce.
// XCD-swizzled blockIdx (bijective: 2048 % 8 == 0) so the 16 blocks of one
// tile-row (sharing halo lines) land on the same XCD's L2.
__global__ __launch_bounds__(256) void hog_hist_kernel(const float* __restrict__ im,
                                                       float* __restrict__ hist) {
    const int bid = (int)(((blockIdx.x & 7) << 8) | (blockIdx.x >> 3));
    const int b  = bid >> 7;
    const int tr = (bid >> 4) & 7;
    const int tc = bid & 15;

    const int t  = threadIdx.x;
    const int cg = t & 7;                  // col group (0..7) -> 4 cols each
    const int rg = t >> 3;                 // row group (0..31) -> 2 rows each

    const int y0 = tr * 64 + rg * 2;       // first px row of this thread
    const int x0 = tc * 32 + cg * 4;       // first px col (float4-aligned)

    const float* imb = im + (size_t)b * NCH * IMG_H * IMG_W;

    // window rows y0-1 .. y0+2 (reflect), as precomputed row offsets
    int yoff[4];
#pragma unroll
    for (int j = 0; j < 4; ++j) yoff[j] = refl(y0 - 1 + j, IMG_H) * IMG_W;
    const int xl = (x0 == 0) ? 1 : x0 - 1;                  // refl(x0-1)
    const int xr = (x0 + 4 >= IMG_W) ? IMG_W - 2 : x0 + 4;  // refl(x0+4)

    float be[8], bgx[8], bgy[8];

#pragma unroll
    for (int c = 0; c < NCH; ++c) {
        const float* chp = imb + (size_t)c * (IMG_H * IMG_W);
        float w[4][6];
#pragma unroll
        for (int j = 0; j < 4; ++j) {
            const float* rp = chp + yoff[j];
            const float4 v = *(const float4*)(rp + x0);
            w[j][0] = rp[xl];
            w[j][1] = v.x; w[j][2] = v.y; w[j][3] = v.z; w[j][4] = v.w;
            w[j][5] = rp[xr];
        }
#pragma unroll
        for (int p = 0; p < 2; ++p) {
#pragma unroll
            for (int q = 0; q < 4; ++q) {
                const int ix = p * 4 + q;
                // identical association to the verified kernel:
                float gx = ((w[p][q + 2] - w[p][q]) + 2.0f * (w[p + 1][q + 2] - w[p + 1][q]))
                         + (w[p + 2][q + 2] - w[p + 2][q]);
                float gy = ((w[p + 2][q] - w[p][q]) + 2.0f * (w[p + 2][q + 1] - w[p][q + 1]))
                         + (w[p + 2][q + 2] - w[p][q + 2]);
                float e = gx * gx + gy * gy;
                if (c == 0) {
                    be[ix] = e; bgx[ix] = gx; bgy[ix] = gy;
                } else {
                    bool gt = e > be[ix];          // branch-free cndmask x3
                    be[ix]  = gt ? e  : be[ix];
                    bgx[ix] = gt ? gx : bgx[ix];
                    bgy[ix] = gt ? gy : bgy[ix];
                }
            }
        }
    }

    const float PI_F  = (float)M_PI;
    const float HPI_F = (float)(M_PI / 2.0);
    const float GAIN  = (float)(9.0 / M_PI);
    // minimax odd poly for atan on [0,1], max err ~2e-5 rad
    const float C1  = 0.99997726f, C3 = -0.33262347f, C5 = 0.19354346f;
    const float C7  = -0.11643287f, C9 = 0.05265332f, C11 = -0.01172120f;

    float acc[NBINS];
#pragma unroll
    for (int k = 0; k < NBINS; ++k) acc[k] = 0.0f;

#pragma unroll
    for (int p = 0; p < 8; ++p) {
        float gx = bgx[p], gy = bgy[p];
        float n = __builtin_amdgcn_sqrtf(be[p]);   // raw v_sqrt, <=1 ulp
        float ax = fabsf(gx), ay = fabsf(gy);
        float mn = fminf(ax, ay), mx = fmaxf(ax, ay);
        float r  = mn * __builtin_amdgcn_rcpf(mx + 1e-37f);
        float r2 = r * r;
        float at = r * (C1 + r2 * (C3 + r2 * (C5 + r2 * (C7 + r2 * (C9 + r2 * C11)))));
        if (ay > ax) at = HPI_F - at;
        if ((__float_as_uint(gx) ^ __float_as_uint(gy)) & 0x80000000u) at = PI_F - at;
        // at = atan2(gy,gx) mod pi, in [0, pi]
        float fp = GAIN * at;              // [0, 9]

        // tent binning with clamp folding: bin k gets n * sat(1-|fp-k|);
        // bin 0 wraps: sat(1-fp) + sat(fp-8)   (verified in R8, same absmax)
        float w0 = __saturatef(1.0f - fp) + __saturatef(fp - 8.0f);
        acc[0] = fmaf(w0, n, acc[0]);
#pragma unroll
        for (int k = 1; k < NBINS; ++k) {
            float wk = __saturatef(1.0f - fabsf(fp - (float)k));
            acc[k] = fmaf(wk, n, acc[k]);
        }
    }

    // in-wave butterfly over each cell's 32 lanes:
    // lane bits: 0,1 = cg&3 (cols in cell), 2 = cell col, 3,4,5 = rg&7 (rows)
#pragma unroll
    for (int k = 0; k < NBINS; ++k) acc[k] += __shfl_xor(acc[k], 1, 64);
#pragma unroll
    for (int k = 0; k < NBINS; ++k) acc[k] += __shfl_xor(acc[k], 2, 64);
#pragma unroll
    for (int k = 0; k < NBINS; ++k) acc[k] += __shfl_xor(acc[k], 8, 64);
#pragma unroll
    for (int k = 0; k < NBINS; ++k) acc[k] += __shfl_xor(acc[k], 16, 64);
#pragma unroll
    for (int k = 0; k < NBINS; ++k) acc[k] += __shfl_xor(acc[k], 32, 64);

    const int lane = t & 63;
    if ((lane & 0x3B) == 0) {              // lanes 0 and 4: one per cell
        const int cellX = tc * 2 + (lane >> 2);
        const int cellY = tr * 4 + (t >> 6);
        float* hp = hist + (((size_t)b * HC + cellY) * WC + cellX) * NBINS;
#pragma unroll
        for (int k = 0; k < NBINS; ++k) hp[k] = acc[k] * (1.0f / 256.0f);
    }
}

// One WAVE per output block (4 waves / 256-thread workgroup, grid 3844).
// Lane k<36 holds value k of the 2x2x9 block; two 6-stage shfl_xor
// butterflies compute the L2 and L2-Hys norms; coalesced 36-float store.
__global__ __launch_bounds__(256) void hog_norm_kernel(const float* __restrict__ hist,
                                                       float* __restrict__ out) {
    const int t    = threadIdx.x;
    const int wv   = t >> 6;
    const int lane = t & 63;
    const int idx  = blockIdx.x * 4 + wv;      // 0..15375 (= 4*3844 exactly)

    const int b = idx / (HB * WB);
    const int r = idx - b * (HB * WB);
    const int i = r / WB;
    const int j = r - i * WB;

    float x = 0.0f;
    if (lane < 36) {
        const int cellIdx = lane / NBINS;      // 0..3
        const int bin     = lane - cellIdx * NBINS;
        const int bi = cellIdx >> 1;
        const int bj = cellIdx & 1;
        x = hist[(size_t)(((b * HC) + (i + bi)) * WC + (j + bj)) * NBINS + bin];
    }

    float ss = x * x;
#pragma unroll
    for (int m = 1; m <= 32; m <<= 1) ss += __shfl_xor(ss, m, 64);
    const float inv1 = 1.0f / (sqrtf(ss) + 1e-10f);

    const float tt = fminf(x * inv1, 0.2f);    // 0 for lanes >= 36
    float ss2 = tt * tt;
#pragma unroll
    for (int m = 1; m <= 32; m <<= 1) ss2 += __shfl_xor(ss2, m, 64);
    const float inv2 = 1.0f / (sqrtf(ss2) + 1e-10f);

    if (lane < 36) out[(size_t)idx * 36 + lane] = tt * inv2;
}

extern "C" void kernel_launch(void* const* d_in, const int* in_sizes, int n_in,
                              void* d_out, int out_size, void* d_ws, size_t ws_size,
                              hipStream_t stream) {
    const float* im = (const float*)d_in[0];
    float* out = (float*)d_out;
    float* hist = (float*)d_ws;  // 16*32*32*9 floats = 589,824 bytes

    hog_hist_kernel<<<NB_ * 8 * 16, 256, 0, stream>>>(im, hist);

    int nout_blocks = NB_ * HB * WB;           // 15376
    hog_norm_kernel<<<nout_blocks / 4, 256, 0, stream>>>(hist, out);
}